// Round 1
// 357.811 us; speedup vs baseline: 1.0969x; 1.0969x over previous
//
#include <hip/hip_runtime.h>
#include <cmath>

#define NTOK 1024
#define NH 8
#define DH 64
#define BATCH 4
#define TBL 3969  // 63*63

#define L2E 1.4426950408889634f

typedef __attribute__((ext_vector_type(8))) short short8;
typedef __attribute__((ext_vector_type(4))) float f32x4;

// pack 2 f32 -> 2 bf16 (RNE) hi parts + residual lo parts, 1 instr each pack
__device__ __forceinline__ void cvt2(float a, float b, unsigned& h, unsigned& l) {
  asm("v_cvt_pk_bf16_f32 %0, %1, %2" : "=v"(h) : "v"(a), "v"(b));
  float ra = a - __uint_as_float(h << 16);
  float rb = b - __uint_as_float(h & 0xffff0000u);
  asm("v_cvt_pk_bf16_f32 %0, %1, %2" : "=v"(l) : "v"(ra), "v"(rb));
}

__device__ __forceinline__ void split8_pk(const float* v, short8& h8, short8& l8) {
  union { short8 s; unsigned u[4]; } H, L;
#pragma unroll
  for (int j = 0; j < 4; ++j) {
    unsigned hp, lp;
    cvt2(v[2 * j], v[2 * j + 1], hp, lp);
    H.u[j] = hp; L.u[j] = lp;
  }
  h8 = H.s; l8 = L.s;
}

__device__ __forceinline__ f32x4 mfma16(short8 a, short8 b, f32x4 c) {
  return __builtin_amdgcn_mfma_f32_16x16x32_bf16(a, b, c, 0, 0, 0);
}

// global->LDS direct copy, 16B per lane (wave-uniform LDS base + lane*16)
__device__ __forceinline__ void gload16(const unsigned short* g, unsigned short* l) {
  __builtin_amdgcn_global_load_lds(
      (__attribute__((address_space(1))) unsigned int*)(g),
      (__attribute__((address_space(3))) unsigned int*)(l), 16, 0, 0);
}

__device__ __forceinline__ void fma4x4(float acc[4][4], const float4& av, const float4& bv) {
  const float a4[4] = {av.x, av.y, av.z, av.w};
  const float b4[4] = {bv.x, bv.y, bv.z, bv.w};
#pragma unroll
  for (int u = 0; u < 4; ++u)
#pragma unroll
    for (int v = 0; v < 4; ++v) acc[u][v] += a4[u] * b4[v];
}

// ---------------- Kernel 0: combined RPE table (log2-domain) ----------------
__global__ void k_comb(const float* __restrict__ t1, const float* __restrict__ t2,
                       const float* __restrict__ sita, const float* __restrict__ dis,
                       float* __restrict__ comb, float* __restrict__ combe) {
  int idx = blockIdx.x * 256 + threadIdx.x;
  if (idx >= TBL) return;
  int dy = idx / 63 - 31, dx = idx % 63 - 31;
  int yi = dy > 0 ? dy : 0, yj = dy > 0 ? 0 : -dy;
  int xi = dx > 0 ? dx : 0, xj = dx > 0 ? 0 : -dx;
  float dv = dis[(size_t)(yi * 32 + xi) * NTOK + (yj * 32 + xj)];
#pragma unroll
  for (int h = 0; h < NH; ++h) {
    float ita = sita[h];
    float factor = 1.0f / (2.0f * ita * ita + 1e-6f);
    float bi = t1[idx * 8 + h] * t2[idx * 8 + h];
    float v = bi + 0.01f * expf(-factor * dv);
    comb[(size_t)h * TBL + idx] = v * L2E;   // log2 domain logit
    combe[(size_t)h * TBL + idx] = expf(v);  // linear multiplicative factor
  }
}

// ---------------- Kernel 1: QKV GEMM (fp32) + K/V split-bf16 emit ----------------
// Q: fp32 (b,h,tok,d). K: per (b,h,tile) swizzled [tok][d] bf16 hi(4KB)+lo(4KB).
// V: per (b,h,tile) swizzled, TRANSPOSED [d][tok] bf16 hi+lo.
// Swizzle: 16B unit index u at row r stored at physical unit u^(r&7).
__global__ __launch_bounds__(256) void k_qkv(const float* __restrict__ x,
                                             const float* __restrict__ w,
                                             float* __restrict__ qf,
                                             unsigned short* __restrict__ kspl,
                                             unsigned short* __restrict__ vspl) {
  __shared__ float As[32][68];
  __shared__ float Bs[32][68];
  const int bx = blockIdx.x;  // 0..23
  const int by = blockIdx.y;  // 0..63
  const int t = threadIdx.x;
  const int tx = t & 15, ty = t >> 4;
  const int m0 = by * 64, n0 = bx * 64;
  float acc[4][4] = {};
  for (int k0 = 0; k0 < 512; k0 += 32) {
#pragma unroll
    for (int l = 0; l < 2; ++l) {
      int idx = t + l * 256;
      {
        int row = idx >> 3, c4 = idx & 7;
        float4 a = *(const float4*)(x + (size_t)(m0 + row) * 512 + k0 + c4 * 4);
        As[c4 * 4 + 0][row] = a.x; As[c4 * 4 + 1][row] = a.y;
        As[c4 * 4 + 2][row] = a.z; As[c4 * 4 + 3][row] = a.w;
      }
      {
        int row = idx >> 4, c4 = idx & 15;
        *(float4*)(&Bs[row][c4 * 4]) =
            *(const float4*)(w + (size_t)(k0 + row) * 1536 + n0 + c4 * 4);
      }
    }
    __syncthreads();
#pragma unroll
    for (int kk = 0; kk < 32; ++kk) {
      float4 av = *(const float4*)(&As[kk][ty * 4]);
      float4 bv = *(const float4*)(&Bs[kk][tx * 4]);
      fma4x4(acc, av, bv);
    }
    __syncthreads();
  }
  const int part = bx >> 3;
  const int h = bx & 7;
  if (part == 0) {  // Q fp32
#pragma unroll
    for (int u = 0; u < 4; ++u) {
      int m = m0 + ty * 4 + u;
      int b = m >> 10, i = m & 1023;
      float4 val;
      val.x = acc[u][0]; val.y = acc[u][1]; val.z = acc[u][2]; val.w = acc[u][3];
      *(float4*)(qf + ((size_t)((b * NH + h) * NTOK + i)) * DH + tx * 4) = val;
    }
  } else if (part == 1) {  // K split bf16, [tok][d] swizzled
    const int b = m0 >> 10;
    const int tile = (m0 & 1023) >> 6;
    unsigned short* base = kspl + ((size_t)((b * NH + h) * 16 + tile) * 2) * 4096;
    const int un = tx >> 1, wo = (tx & 1) * 4;
#pragma unroll
    for (int u = 0; u < 4; ++u) {
      int row = ty * 4 + u;
      int sz = un ^ (row & 7);
      unsigned h0, h1, l0, l1;
      cvt2(acc[u][0], acc[u][1], h0, l0);
      cvt2(acc[u][2], acc[u][3], h1, l1);
      *(uint2*)(base + row * 64 + sz * 8 + wo) = make_uint2(h0, h1);
      *(uint2*)(base + 4096 + row * 64 + sz * 8 + wo) = make_uint2(l0, l1);
    }
  } else {  // V split bf16, transposed [d][tok] swizzled
    const int b = m0 >> 10;
    const int tile = (m0 & 1023) >> 6;
    unsigned short* base = vspl + ((size_t)((b * NH + h) * 16 + tile) * 2) * 4096;
    const int un = ty >> 1, wo = (ty & 1) * 4;
#pragma unroll
    for (int v = 0; v < 4; ++v) {
      int d = tx * 4 + v;
      int sz = un ^ (d & 7);
      unsigned h0, h1, l0, l1;
      cvt2(acc[0][v], acc[1][v], h0, l0);
      cvt2(acc[2][v], acc[3][v], h1, l1);
      *(uint2*)(base + d * 64 + sz * 8 + wo) = make_uint2(h0, h1);
      *(uint2*)(base + 4096 + d * 64 + sz * 8 + wo) = make_uint2(l0, l1);
    }
  }
}

// ---------------- Kernel 2: fused attention (log2 domain, gload_lds staging) ----
__global__ __launch_bounds__(256, 2) void k_attn(
    const float* __restrict__ qf, const unsigned short* __restrict__ kspl,
    const unsigned short* __restrict__ vspl, const float* __restrict__ prob,
    const float* __restrict__ comb, const float* __restrict__ combe,
    const float* __restrict__ wt,
    float* __restrict__ attn0, float* __restrict__ o) {
  __shared__ unsigned short KhS[4096], KlS[4096];  // K [tok][d] bf16 hi/lo (swizzled)
  __shared__ unsigned short VhS[4096], VlS[4096];  // V^T [d][tok] bf16 hi/lo (swizzled)
  __shared__ float PfS[64 * 68];                   // P [row][jj] fp32
  __shared__ float2 csS[3 * 64];                   // (comb*log2e, exp(comb)) slice
  __shared__ float thrS[64];

  const int rt = blockIdx.x;   // 0..15 row tile
  const int bh = blockIdx.y;   // 0..31
  const int b = bh >> 3, h = bh & 7;
  const int i0 = rt * 64;
  const int t = threadIdx.x;
  const int w = t >> 6;        // wave 0..3 -> rows 16w..16w+15
  const int lane = t & 63;
  const int q = lane >> 4, li = lane & 15;
  const float* qb = qf + (size_t)bh * NTOK * DH;
  const float* ch = comb + (size_t)h * TBL;
  const float* che = combe + (size_t)h * TBL;
  const int rbase = (i0 >> 5) + 30;

  // thresh_raw = sigmoid(q . W_thresh) * sigmoid(-2)
  {
    int row = t >> 2, dg = t & 3;
    const float* qr2 = qb + (size_t)(i0 + row) * DH + dg * 16;
    float sum = 0.f;
#pragma unroll
    for (int c = 0; c < 16; ++c) sum += qr2[c] * wt[dg * 16 + c];
    sum += __shfl_xor(sum, 1);
    sum += __shfl_xor(sum, 2);
    if (dg == 0)
      thrS[row] = (1.0f / (1.0f + exp2f(-sum * L2E))) * 0.11920292202211755f;
  }

  // Q fragments (A-layout: m=li, k=32c+8q+j), prescaled by 0.125*log2e
  short8 qah[2], qal[2];
  {
    const float* qr2 = qb + (size_t)(i0 + 16 * w + li) * DH;
    const float QS = 0.125f * L2E;
#pragma unroll
    for (int c = 0; c < 2; ++c) {
      float4 a = *(const float4*)(qr2 + 32 * c + 8 * q);
      float4 bb = *(const float4*)(qr2 + 32 * c + 8 * q + 4);
      float tmp[8] = {a.x * QS, a.y * QS, a.z * QS, a.w * QS,
                      bb.x * QS, bb.y * QS, bb.z * QS, bb.w * QS};
      split8_pk(tmp, qah[c], qal[c]);
    }
  }

  // per-lane online stats (log2 domain), row_local = 16w + 4q + r
  float m0l[4], s0l[4], ml[4], sl[4], mnl[4];
#pragma unroll
  for (int r = 0; r < 4; ++r) {
    m0l[r] = -1e30f; ml[r] = -1e30f; mnl[r] = 1e30f;
    s0l[r] = 0.f; sl[r] = 0.f;
  }

  // ================= pass 1: stats =================
#pragma unroll 1
  for (int j0 = 0; j0 < NTOK; j0 += 64) {
    const unsigned short* gk = kspl + ((size_t)(bh * 16 + (j0 >> 6)) * 2) * 4096;
#pragma unroll
    for (int jl = 0; jl < 2; ++jl) {
      int seg = 2 * w + jl;
      gload16(gk + seg * 512 + lane * 8, KhS + seg * 512);
      gload16(gk + 4096 + seg * 512 + lane * 8, KlS + seg * 512);
    }
    if (t < 192) {
      int rl2 = t >> 6, c2 = t & 63;
      if (c2 < 63) {
        int off = (rbase - (j0 >> 5) + rl2) * 63 + c2;
        csS[rl2 * 64 + c2] = make_float2(ch[off], che[off]);
      }
    }
    __syncthreads();

    f32x4 acc[4] = {};
#pragma unroll
    for (int c = 0; c < 2; ++c) {
#pragma unroll
      for (int T = 0; T < 4; ++T) {
        int ro = (16 * T + li) * 64 + ((4 * c + q) ^ (li & 7)) * 8;
        short8 bh8 = *(const short8*)(KhS + ro);
        short8 bl8 = *(const short8*)(KlS + ro);
        acc[T] = mfma16(qah[c], bh8, acc[T]);
        acc[T] = mfma16(qah[c], bl8, acc[T]);
        acc[T] = mfma16(qal[c], bh8, acc[T]);
      }
    }

    float2 ce[4][4];
    float t0[4], tt[4], tmn[4];
#pragma unroll
    for (int r = 0; r < 4; ++r) { t0[r] = -1e30f; tt[r] = -1e30f; tmn[r] = 1e30f; }
#pragma unroll
    for (int T = 0; T < 4; ++T) {
      int jj = 16 * T + li;
#pragma unroll
      for (int r = 0; r < 4; ++r) {
        int il = 16 * w + 4 * q + r;
        int rl2 = (il >> 5) - (jj >> 5) + 1;
        int cc2 = (il & 31) - (jj & 31) + 31;
        ce[T][r] = csS[rl2 * 64 + cc2];
        float d0 = acc[T][r];
        float dt = d0 + ce[T][r].x;
        t0[r] = fmaxf(t0[r], d0);
        tt[r] = fmaxf(tt[r], dt);
        tmn[r] = fminf(tmn[r], dt);
      }
    }
#pragma unroll
    for (int r = 0; r < 4; ++r) {
      float nm0 = fmaxf(m0l[r], t0[r]);
      float nm = fmaxf(ml[r], tt[r]);
      float sc0 = exp2f(m0l[r] - nm0), sc = exp2f(ml[r] - nm), k0 = exp2f(nm0 - nm);
      float s0a = 0.f, sEa = 0.f;
#pragma unroll
      for (int T = 0; T < 4; ++T) {
        float e0 = exp2f(acc[T][r] - nm0);
        s0a += e0;
        sEa += e0 * ce[T][r].y;
      }
      s0l[r] = s0l[r] * sc0 + s0a;
      sl[r] = sl[r] * sc + sEa * k0;
      m0l[r] = nm0; ml[r] = nm; mnl[r] = fminf(mnl[r], tmn[r]);
    }
    __syncthreads();
  }

  // ================= finalize per-row =================
  float m0f[4], is0f[4], thf[4], crf[4];
#pragma unroll
  for (int r = 0; r < 4; ++r) {
    float m0v = m0l[r], s0 = s0l[r], m = ml[r], s = sl[r], mn = mnl[r];
#pragma unroll
    for (int off = 1; off < 16; off <<= 1) {
      float om = __shfl_xor(m0v, off), os = __shfl_xor(s0, off);
      float n0 = fmaxf(m0v, om);
      s0 = s0 * exp2f(m0v - n0) + os * exp2f(om - n0);
      m0v = n0;
      float om2 = __shfl_xor(m, off), os2 = __shfl_xor(s, off);
      float n2 = fmaxf(m, om2);
      s = s * exp2f(m - n2) + os2 * exp2f(om2 - n2);
      m = n2;
      mn = fminf(mn, __shfl_xor(mn, off));
    }
    float isf = 1.f / s;
    float amin = exp2f(mn - m) * isf;
    int rloc = 16 * w + 4 * q + r;
    float th = amin + thrS[rloc] * (isf - amin);
    if (prob[b * NTOK + i0 + rloc] >= 0.9f) th = 1e30f;
    m0f[r] = m0v; is0f[r] = 1.f / s0; thf[r] = th; crf[r] = exp2f(m0v - m) * isf;
  }

  // ================= pass 2: attn0, P, PV =================
  f32x4 oacc[4] = {};
  float denl[4] = {0.f, 0.f, 0.f, 0.f};
#pragma unroll 1
  for (int j0 = 0; j0 < NTOK; j0 += 64) {
    const unsigned short* gk = kspl + ((size_t)(bh * 16 + (j0 >> 6)) * 2) * 4096;
    const unsigned short* gv = vspl + ((size_t)(bh * 16 + (j0 >> 6)) * 2) * 4096;
#pragma unroll
    for (int jl = 0; jl < 2; ++jl) {
      int seg = 2 * w + jl;
      gload16(gk + seg * 512 + lane * 8, KhS + seg * 512);
      gload16(gk + 4096 + seg * 512 + lane * 8, KlS + seg * 512);
      gload16(gv + seg * 512 + lane * 8, VhS + seg * 512);
      gload16(gv + 4096 + seg * 512 + lane * 8, VlS + seg * 512);
    }
    if (t < 192) {
      int rl2 = t >> 6, c2 = t & 63;
      if (c2 < 63) {
        int off = (rbase - (j0 >> 5) + rl2) * 63 + c2;
        csS[rl2 * 64 + c2] = make_float2(ch[off], che[off]);
      }
    }
    __syncthreads();

    f32x4 acc[4] = {};
#pragma unroll
    for (int c = 0; c < 2; ++c) {
#pragma unroll
      for (int T = 0; T < 4; ++T) {
        int ro = (16 * T + li) * 64 + ((4 * c + q) ^ (li & 7)) * 8;
        short8 bh8 = *(const short8*)(KhS + ro);
        short8 bl8 = *(const short8*)(KlS + ro);
        acc[T] = mfma16(qah[c], bh8, acc[T]);
        acc[T] = mfma16(qah[c], bl8, acc[T]);
        acc[T] = mfma16(qal[c], bh8, acc[T]);
      }
    }

#pragma unroll
    for (int T = 0; T < 4; ++T) {
      int jj = 16 * T + li;
#pragma unroll
      for (int r = 0; r < 4; ++r) {
        int il = 16 * w + 4 * q + r;
        int rl2 = (il >> 5) - (jj >> 5) + 1;
        int cc2 = (il & 31) - (jj & 31) + 31;
        float ey = csS[rl2 * 64 + cc2].y;
        float e0 = exp2f(acc[T][r] - m0f[r]);
        __builtin_nontemporal_store(
            e0 * is0f[r],
            attn0 + (size_t)(bh * NTOK + i0 + il) * NTOK + j0 + jj);
        float at = e0 * ey * crf[r];
        float p = (at - thf[r] > 0.f) ? at : 0.f;
        denl[r] += p;
        PfS[il * 68 + jj] = p;
      }
    }
    // PV: A = P (same-wave private region), B = V^T frags
#pragma unroll
    for (int c = 0; c < 2; ++c) {
      const float* pp = PfS + (16 * w + li) * 68 + 32 * c + 8 * q;
      float pv8[8];
      *(float4*)(pv8) = *(const float4*)pp;
      *(float4*)(pv8 + 4) = *(const float4*)(pp + 4);
      short8 pah, pal;
      split8_pk(pv8, pah, pal);
#pragma unroll
      for (int T = 0; T < 4; ++T) {
        int ro = (16 * T + li) * 64 + ((4 * c + q) ^ (li & 7)) * 8;
        short8 vh8 = *(const short8*)(VhS + ro);
        short8 vl8 = *(const short8*)(VlS + ro);
        oacc[T] = mfma16(pah, vh8, oacc[T]);
        oacc[T] = mfma16(pah, vl8, oacc[T]);
        oacc[T] = mfma16(pal, vh8, oacc[T]);
      }
    }
    __syncthreads();
  }

  // scale by 1/(deno+1e-6), store o in (b,n,h,d)
#pragma unroll
  for (int r = 0; r < 4; ++r) {
    float dsum = denl[r];
#pragma unroll
    for (int off = 1; off < 16; off <<= 1) dsum += __shfl_xor(dsum, off);
    float pf = 1.f / (dsum + 1e-6f);
    int row = i0 + 16 * w + 4 * q + r;
#pragma unroll
    for (int T = 0; T < 4; ++T) {
      o[(((size_t)b * NTOK + row) * NH + h) * DH + 16 * T + li] = oacc[T][r] * pf;
    }
  }
}

// ---------------- Kernel 3: output GEMM (fp32) ----------------
__global__ __launch_bounds__(256) void k_out(const float* __restrict__ a,
                                             const float* __restrict__ w,
                                             const float* __restrict__ bias,
                                             float* __restrict__ c) {
  __shared__ float As[32][68];
  __shared__ float Bs[32][68];
  const int bx = blockIdx.x;
  const int by = blockIdx.y;
  const int t = threadIdx.x;
  const int tx = t & 15, ty = t >> 4;
  const int m0 = by * 64, n0 = bx * 64;
  float acc[4][4] = {};
  for (int k0 = 0; k0 < 512; k0 += 32) {
#pragma unroll
    for (int l = 0; l < 2; ++l) {
      int idx = t + l * 256;
      {
        int row = idx >> 3, c4 = idx & 7;
        float4 av = *(const float4*)(a + (size_t)(m0 + row) * 512 + k0 + c4 * 4);
        As[c4 * 4 + 0][row] = av.x; As[c4 * 4 + 1][row] = av.y;
        As[c4 * 4 + 2][row] = av.z; As[c4 * 4 + 3][row] = av.w;
      }
      {
        int row = idx >> 4, c4 = idx & 15;
        *(float4*)(&Bs[row][c4 * 4]) =
            *(const float4*)(w + (size_t)(k0 + row) * 512 + n0 + c4 * 4);
      }
    }
    __syncthreads();
#pragma unroll
    for (int kk = 0; kk < 32; ++kk) {
      float4 av = *(const float4*)(&As[kk][ty * 4]);
      float4 bv = *(const float4*)(&Bs[kk][tx * 4]);
      fma4x4(acc, av, bv);
    }
    __syncthreads();
  }
  float4 bv4 = *(const float4*)(bias + n0 + tx * 4);
#pragma unroll
  for (int u = 0; u < 4; ++u) {
    int m = m0 + ty * 4 + u;
    float4 val;
    val.x = acc[u][0] + bv4.x; val.y = acc[u][1] + bv4.y;
    val.z = acc[u][2] + bv4.z; val.w = acc[u][3] + bv4.w;
    *(float4*)(c + (size_t)m * 512 + n0 + tx * 4) = val;
  }
}

extern "C" void kernel_launch(void* const* d_in, const int* in_sizes, int n_in,
                              void* d_out, int out_size, void* d_ws, size_t ws_size,
                              hipStream_t stream) {
  const float* x    = (const float*)d_in[0];
  const float* prob = (const float*)d_in[1];
  const float* wqkv = (const float*)d_in[2];
  const float* t1   = (const float*)d_in[3];
  const float* t2   = (const float*)d_in[4];
  const float* sita = (const float*)d_in[5];
  const float* wt   = (const float*)d_in[6];
  const float* wout = (const float*)d_in[7];
  const float* bout = (const float*)d_in[8];
  const float* dis  = (const float*)d_in[10];

  float* out = (float*)d_out;
  float* attn0 = out + (size_t)BATCH * NTOK * 512;

  float* comb = (float*)d_ws;                         // 32768 floats (log2 domain)
  float* combe = comb + 32768;                        // 32768 floats
  float* qf = combe + 32768;                          // 2,097,152 floats (Q fp32)
  unsigned short* kspl = (unsigned short*)(qf + (size_t)BATCH * NH * NTOK * DH);  // 8 MB
  unsigned short* vspl = kspl + (size_t)4194304;                                  // 8 MB
  float* o = (float*)(vspl + (size_t)4194304);        // 2,097,152 floats

  hipLaunchKernelGGL(k_comb, dim3(16), dim3(256), 0, stream, t1, t2, sita, dis, comb, combe);
  hipLaunchKernelGGL(k_qkv, dim3(24, 64), dim3(256), 0, stream, x, wqkv, qf, kspl, vspl);
  hipLaunchKernelGGL(k_attn, dim3(16, 32), dim3(256), 0, stream,
                     qf, kspl, vspl, prob, comb, combe, wt, attn0, o);
  hipLaunchKernelGGL(k_out, dim3(8, 64), dim3(256), 0, stream, o, wout, bout, out);
}

// Round 2
// 281.364 us; speedup vs baseline: 1.3949x; 1.2717x over previous
//
#include <hip/hip_runtime.h>
#include <cmath>

#define NTOK 1024
#define NH 8
#define DH 64
#define BATCH 4
#define TBL 3969  // 63*63

#define L2E 1.4426950408889634f

typedef __attribute__((ext_vector_type(8))) short short8;
typedef __attribute__((ext_vector_type(4))) float f32x4;

__device__ __forceinline__ unsigned bf16rne(float x) {
  unsigned u = __float_as_uint(x);
  return (u + 0x7fffu + ((u >> 16) & 1u)) >> 16;
}

// pack 2 f32 -> 2 bf16 (RNE) hi parts + residual lo parts, 1 instr each pack
__device__ __forceinline__ void cvt2(float a, float b, unsigned& h, unsigned& l) {
  asm("v_cvt_pk_bf16_f32 %0, %1, %2" : "=v"(h) : "v"(a), "v"(b));
  float ra = a - __uint_as_float(h << 16);
  float rb = b - __uint_as_float(h & 0xffff0000u);
  asm("v_cvt_pk_bf16_f32 %0, %1, %2" : "=v"(l) : "v"(ra), "v"(rb));
}

__device__ __forceinline__ void split8_pk(const float* v, short8& h8, short8& l8) {
  union { short8 s; unsigned u[4]; } H, L;
#pragma unroll
  for (int j = 0; j < 4; ++j) {
    unsigned hp, lp;
    cvt2(v[2 * j], v[2 * j + 1], hp, lp);
    H.u[j] = hp; L.u[j] = lp;
  }
  h8 = H.s; l8 = L.s;
}

__device__ __forceinline__ f32x4 mfma16(short8 a, short8 b, f32x4 c) {
  return __builtin_amdgcn_mfma_f32_16x16x32_bf16(a, b, c, 0, 0, 0);
}

// global->LDS direct copy, 16B per lane (wave-uniform LDS base + lane*16)
__device__ __forceinline__ void gload16(const unsigned short* g, unsigned short* l) {
  __builtin_amdgcn_global_load_lds(
      (__attribute__((address_space(1))) unsigned int*)(g),
      (__attribute__((address_space(3))) unsigned int*)(l), 16, 0, 0);
}

// ---------------- Kernel 0: combined RPE table (log2-domain) ----------------
__global__ void k_comb(const float* __restrict__ t1, const float* __restrict__ t2,
                       const float* __restrict__ sita, const float* __restrict__ dis,
                       float* __restrict__ comb, float* __restrict__ combe) {
  int idx = blockIdx.x * 256 + threadIdx.x;
  if (idx >= TBL) return;
  int dy = idx / 63 - 31, dx = idx % 63 - 31;
  int yi = dy > 0 ? dy : 0, yj = dy > 0 ? 0 : -dy;
  int xi = dx > 0 ? dx : 0, xj = dx > 0 ? 0 : -dx;
  float dv = dis[(size_t)(yi * 32 + xi) * NTOK + (yj * 32 + xj)];
#pragma unroll
  for (int h = 0; h < NH; ++h) {
    float ita = sita[h];
    float factor = 1.0f / (2.0f * ita * ita + 1e-6f);
    float bi = t1[idx * 8 + h] * t2[idx * 8 + h];
    float v = bi + 0.01f * expf(-factor * dv);
    comb[(size_t)h * TBL + idx] = v * L2E;   // log2 domain logit
    combe[(size_t)h * TBL + idx] = expf(v);  // linear multiplicative factor
  }
}

// ---------------- Kernel 0b: convert x / transpose+convert weights -------------
// blocks [0,1024): x [4096][512] -> xh/xl linear bf16 split
// blocks [1024,1216): W_qkv [512][1536] -> wth/wtl [1536][512]
// blocks [1216,1280): W_out [512][512] -> wouth/woutl [512][512]
__global__ __launch_bounds__(256) void k_prep(
    const float* __restrict__ x, const float* __restrict__ wqkv,
    const float* __restrict__ wout,
    unsigned short* __restrict__ xh, unsigned short* __restrict__ xl,
    unsigned short* __restrict__ wth, unsigned short* __restrict__ wtl,
    unsigned short* __restrict__ wouth, unsigned short* __restrict__ woutl) {
  const int bid = blockIdx.x;
  const int t = threadIdx.x;
  if (bid < 1024) {
    size_t base = ((size_t)bid * 256 + t) * 8;
    float v8[8];
    *(float4*)(v8) = *(const float4*)(x + base);
    *(float4*)(v8 + 4) = *(const float4*)(x + base + 4);
    short8 h8, l8;
    split8_pk(v8, h8, l8);
    *(short8*)(xh + base) = h8;
    *(short8*)(xl + base) = l8;
    return;
  }
  __shared__ float tile[64][65];
  const float* src;
  unsigned short *dh, *dl;
  int n0, k0, N;
  if (bid < 1216) {
    int b2 = bid - 1024;
    n0 = (b2 % 24) * 64; k0 = (b2 / 24) * 64; N = 1536;
    src = wqkv; dh = wth; dl = wtl;
  } else {
    int b2 = bid - 1216;
    n0 = (b2 % 8) * 64; k0 = (b2 / 8) * 64; N = 512;
    src = wout; dh = wouth; dl = woutl;
  }
#pragma unroll
  for (int l = 0; l < 4; ++l) {
    int idx = t + l * 256;
    int r = idx >> 4, c4 = idx & 15;
    float4 v = *(const float4*)(src + (size_t)(k0 + r) * N + n0 + c4 * 4);
    tile[r][c4 * 4 + 0] = v.x; tile[r][c4 * 4 + 1] = v.y;
    tile[r][c4 * 4 + 2] = v.z; tile[r][c4 * 4 + 3] = v.w;
  }
  __syncthreads();
#pragma unroll
  for (int l = 0; l < 2; ++l) {
    int idx = t + l * 256;
    int n = idx >> 3, c8 = idx & 7;
    float v8[8];
#pragma unroll
    for (int j = 0; j < 8; ++j) v8[j] = tile[c8 * 8 + j][n];
    short8 h8, l8;
    split8_pk(v8, h8, l8);
    *(short8*)(dh + (size_t)(n0 + n) * 512 + k0 + c8 * 8) = h8;
    *(short8*)(dl + (size_t)(n0 + n) * 512 + k0 + c8 * 8) = l8;
  }
}

// ---------------- shared MFMA GEMM core (split-bf16, 128x128 tile, K=512) ------
// A,B stored [row][512] bf16 row-major (hi/lo arrays). Stages 128x64 tiles via
// global_load_lds, XOR-swizzled (16B unit u at row r stored at u^(r&7)).
// acc[mt][nt]: D[m = 64*(w>>1)+16mt+4q+j][n = 64*(w&1)+16nt+li].
__device__ __forceinline__ void gemm_core(
    const unsigned short* pAh, const unsigned short* pAl,
    const unsigned short* pBh, const unsigned short* pBl,
    int a0, int b0, int w, int lane, f32x4 acc[4][4],
    unsigned short* AhS, unsigned short* AlS,
    unsigned short* BhS, unsigned short* BlS) {
  const int q = lane >> 4, li = lane & 15;
  const int wr = w >> 1, wc = w & 1;
#pragma unroll 1
  for (int k0 = 0; k0 < 512; k0 += 64) {
#pragma unroll
    for (int l = 0; l < 4; ++l) {
      int idx = w * 256 + l * 64 + lane;
      int row = idx >> 3, u = idx & 7;
      int so = k0 + ((u ^ (row & 7)) * 8);
      int db = (w * 256 + l * 64) * 8;
      gload16(pAh + (size_t)(a0 + row) * 512 + so, AhS + db);
      gload16(pAl + (size_t)(a0 + row) * 512 + so, AlS + db);
      gload16(pBh + (size_t)(b0 + row) * 512 + so, BhS + db);
      gload16(pBl + (size_t)(b0 + row) * 512 + so, BlS + db);
    }
    __syncthreads();
#pragma unroll
    for (int c = 0; c < 2; ++c) {
      short8 aH[4], aL[4], bH[4], bL[4];
#pragma unroll
      for (int mt = 0; mt < 4; ++mt) {
        int row = 64 * wr + 16 * mt + li;
        int ro = row * 64 + (((4 * c + q) ^ (row & 7)) * 8);
        aH[mt] = *(const short8*)(AhS + ro);
        aL[mt] = *(const short8*)(AlS + ro);
        int rowb = 64 * wc + 16 * mt + li;
        int rob = rowb * 64 + (((4 * c + q) ^ (rowb & 7)) * 8);
        bH[mt] = *(const short8*)(BhS + rob);
        bL[mt] = *(const short8*)(BlS + rob);
      }
#pragma unroll
      for (int mt = 0; mt < 4; ++mt)
#pragma unroll
        for (int nt = 0; nt < 4; ++nt) {
          acc[mt][nt] = mfma16(aH[mt], bH[nt], acc[mt][nt]);
          acc[mt][nt] = mfma16(aH[mt], bL[nt], acc[mt][nt]);
          acc[mt][nt] = mfma16(aL[mt], bH[nt], acc[mt][nt]);
        }
    }
    __syncthreads();
  }
}

// ---------------- Kernel 1: QKV GEMM (split-bf16 MFMA) ----------------
// grid (12, 32). bx: 128-col tile over N=1536 (part = bx>>2). by: 128-token tile.
// parts 0 (Q), 1 (K): swapped orientation (A = W^T, B = x) -> lane holds 4
// consecutive d for one token. part 2 (V): normal (A = x, B = W^T) -> lane
// holds 4 consecutive tokens for one d (feeds V^T layout).
__global__ __launch_bounds__(256, 2) void k_qkv(
    const unsigned short* __restrict__ xh, const unsigned short* __restrict__ xl,
    const unsigned short* __restrict__ wth, const unsigned short* __restrict__ wtl,
    float* __restrict__ qf, unsigned short* __restrict__ kspl,
    unsigned short* __restrict__ vspl) {
  __shared__ unsigned short AhS[8192], AlS[8192], BhS[8192], BlS[8192];
  const int bx = blockIdx.x, by = blockIdx.y;
  const int part = bx >> 2;
  const int t = threadIdx.x;
  const int w = t >> 6, lane = t & 63;
  const int q = lane >> 4, li = lane & 15;
  const int wr = w >> 1, wc = w & 1;
  f32x4 acc[4][4] = {};
  if (part < 2)
    gemm_core(wth, wtl, xh, xl, bx * 128, by * 128, w, lane, acc, AhS, AlS, BhS, BlS);
  else
    gemm_core(xh, xl, wth, wtl, by * 128, bx * 128, w, lane, acc, AhS, AlS, BhS, BlS);

  if (part == 0) {
    int hq = bx * 2 + wr;
#pragma unroll
    for (int nt = 0; nt < 4; ++nt) {
      int tok = by * 128 + 64 * wc + 16 * nt + li;
      int b = tok >> 10, i = tok & 1023;
#pragma unroll
      for (int mt = 0; mt < 4; ++mt) {
        int d0 = 16 * mt + 4 * q;
        float4 v;
        v.x = acc[mt][nt][0]; v.y = acc[mt][nt][1];
        v.z = acc[mt][nt][2]; v.w = acc[mt][nt][3];
        *(float4*)(qf + ((size_t)(b * NH + hq) * NTOK + i) * DH + d0) = v;
      }
    }
  } else if (part == 1) {
    int hq = bx * 2 + wr - 8;
#pragma unroll
    for (int nt = 0; nt < 4; ++nt) {
      int tok = by * 128 + 64 * wc + 16 * nt + li;
      int b = tok >> 10, tile = (tok & 1023) >> 6, tl = tok & 63;
      unsigned short* kb = kspl + ((size_t)((b * NH + hq) * 16 + tile) * 2) * 4096;
#pragma unroll
      for (int mt = 0; mt < 4; ++mt) {
        int d0 = 16 * mt + 4 * q;
        int pu = (d0 >> 3) ^ (tl & 7), off = d0 & 7;
        unsigned h0, h1, l0, l1;
        cvt2(acc[mt][nt][0], acc[mt][nt][1], h0, l0);
        cvt2(acc[mt][nt][2], acc[mt][nt][3], h1, l1);
        *(uint2*)(kb + tl * 64 + pu * 8 + off) = make_uint2(h0, h1);
        *(uint2*)(kb + 4096 + tl * 64 + pu * 8 + off) = make_uint2(l0, l1);
      }
    }
  } else {
    int hq = (bx - 8) * 2 + wc;
#pragma unroll
    for (int mt = 0; mt < 4; ++mt) {
      int tok0 = by * 128 + 64 * wr + 16 * mt + 4 * q;
      int b = tok0 >> 10, tile = (tok0 & 1023) >> 6, tl0 = tok0 & 63;
      int lu = tl0 >> 3, off = tl0 & 7;
#pragma unroll
      for (int nt = 0; nt < 4; ++nt) {
        int d = 16 * nt + li;
        unsigned short* vb = vspl + ((size_t)((b * NH + hq) * 16 + tile) * 2) * 4096;
        int pu = lu ^ (d & 7);
        unsigned h0, h1, l0, l1;
        cvt2(acc[mt][nt][0], acc[mt][nt][1], h0, l0);
        cvt2(acc[mt][nt][2], acc[mt][nt][3], h1, l1);
        *(uint2*)(vb + d * 64 + pu * 8 + off) = make_uint2(h0, h1);
        *(uint2*)(vb + 4096 + d * 64 + pu * 8 + off) = make_uint2(l0, l1);
      }
    }
  }
}

// ---------------- Kernel 2: fused attention (log2 domain, gload_lds staging) ----
__global__ __launch_bounds__(256, 2) void k_attn(
    const float* __restrict__ qf, const unsigned short* __restrict__ kspl,
    const unsigned short* __restrict__ vspl, const float* __restrict__ prob,
    const float* __restrict__ comb, const float* __restrict__ combe,
    const float* __restrict__ wt,
    float* __restrict__ attn0, unsigned short* __restrict__ oh,
    unsigned short* __restrict__ ol) {
  __shared__ unsigned short KhS[4096], KlS[4096];  // K [tok][d] bf16 hi/lo (swizzled)
  __shared__ unsigned short VhS[4096], VlS[4096];  // V^T [d][jj] swizzled bf16
  __shared__ float PfS[64 * 68];                   // P [row][jj] fp32
  __shared__ float2 csS[3 * 64];                   // (comb*log2e, exp(comb)) slice
  __shared__ float thrS[64];

  const int rt = blockIdx.x;   // 0..15 row tile
  const int bh = blockIdx.y;   // 0..31
  const int b = bh >> 3, h = bh & 7;
  const int i0 = rt * 64;
  const int t = threadIdx.x;
  const int w = t >> 6;        // wave 0..3 -> rows 16w..16w+15
  const int lane = t & 63;
  const int q = lane >> 4, li = lane & 15;
  const float* qb = qf + (size_t)bh * NTOK * DH;
  const float* ch = comb + (size_t)h * TBL;
  const float* che = combe + (size_t)h * TBL;
  const int rbase = (i0 >> 5) + 30;

  // thresh_raw = sigmoid(q . W_thresh) * sigmoid(-2)
  {
    int row = t >> 2, dg = t & 3;
    const float* qr2 = qb + (size_t)(i0 + row) * DH + dg * 16;
    float sum = 0.f;
#pragma unroll
    for (int c = 0; c < 16; ++c) sum += qr2[c] * wt[dg * 16 + c];
    sum += __shfl_xor(sum, 1);
    sum += __shfl_xor(sum, 2);
    if (dg == 0)
      thrS[row] = (1.0f / (1.0f + exp2f(-sum * L2E))) * 0.11920292202211755f;
  }

  // Q fragments (A-layout: m=li, k=32c+8q+j), prescaled by 0.125*log2e
  short8 qah[2], qal[2];
  {
    const float* qr2 = qb + (size_t)(i0 + 16 * w + li) * DH;
    const float QS = 0.125f * L2E;
#pragma unroll
    for (int c = 0; c < 2; ++c) {
      float4 a = *(const float4*)(qr2 + 32 * c + 8 * q);
      float4 bb = *(const float4*)(qr2 + 32 * c + 8 * q + 4);
      float tmp[8] = {a.x * QS, a.y * QS, a.z * QS, a.w * QS,
                      bb.x * QS, bb.y * QS, bb.z * QS, bb.w * QS};
      split8_pk(tmp, qah[c], qal[c]);
    }
  }

  // per-lane online stats (log2 domain), row_local = 16w + 4q + r
  float m0l[4], s0l[4], ml[4], sl[4], mnl[4];
#pragma unroll
  for (int r = 0; r < 4; ++r) {
    m0l[r] = -1e30f; ml[r] = -1e30f; mnl[r] = 1e30f;
    s0l[r] = 0.f; sl[r] = 0.f;
  }

  // ================= pass 1: stats =================
#pragma unroll 1
  for (int j0 = 0; j0 < NTOK; j0 += 64) {
    const unsigned short* gk = kspl + ((size_t)(bh * 16 + (j0 >> 6)) * 2) * 4096;
#pragma unroll
    for (int jl = 0; jl < 2; ++jl) {
      int seg = 2 * w + jl;
      gload16(gk + seg * 512 + lane * 8, KhS + seg * 512);
      gload16(gk + 4096 + seg * 512 + lane * 8, KlS + seg * 512);
    }
    if (t < 192) {
      int rl2 = t >> 6, c2 = t & 63;
      if (c2 < 63) {
        int off = (rbase - (j0 >> 5) + rl2) * 63 + c2;
        csS[rl2 * 64 + c2] = make_float2(ch[off], che[off]);
      }
    }
    __syncthreads();

    f32x4 acc[4] = {};
#pragma unroll
    for (int c = 0; c < 2; ++c) {
#pragma unroll
      for (int T = 0; T < 4; ++T) {
        int ro = (16 * T + li) * 64 + ((4 * c + q) ^ (li & 7)) * 8;
        short8 bh8 = *(const short8*)(KhS + ro);
        short8 bl8 = *(const short8*)(KlS + ro);
        acc[T] = mfma16(qah[c], bh8, acc[T]);
        acc[T] = mfma16(qah[c], bl8, acc[T]);
        acc[T] = mfma16(qal[c], bh8, acc[T]);
      }
    }

    float2 ce[4][4];
    float t0[4], tt[4], tmn[4];
#pragma unroll
    for (int r = 0; r < 4; ++r) { t0[r] = -1e30f; tt[r] = -1e30f; tmn[r] = 1e30f; }
#pragma unroll
    for (int T = 0; T < 4; ++T) {
      int jj = 16 * T + li;
#pragma unroll
      for (int r = 0; r < 4; ++r) {
        int il = 16 * w + 4 * q + r;
        int rl2 = (il >> 5) - (jj >> 5) + 1;
        int cc2 = (il & 31) - (jj & 31) + 31;
        ce[T][r] = csS[rl2 * 64 + cc2];
        float d0 = acc[T][r];
        float dt = d0 + ce[T][r].x;
        t0[r] = fmaxf(t0[r], d0);
        tt[r] = fmaxf(tt[r], dt);
        tmn[r] = fminf(tmn[r], dt);
      }
    }
#pragma unroll
    for (int r = 0; r < 4; ++r) {
      float nm0 = fmaxf(m0l[r], t0[r]);
      float nm = fmaxf(ml[r], tt[r]);
      float sc0 = exp2f(m0l[r] - nm0), sc = exp2f(ml[r] - nm), k0 = exp2f(nm0 - nm);
      float s0a = 0.f, sEa = 0.f;
#pragma unroll
      for (int T = 0; T < 4; ++T) {
        float e0 = exp2f(acc[T][r] - nm0);
        s0a += e0;
        sEa += e0 * ce[T][r].y;
      }
      s0l[r] = s0l[r] * sc0 + s0a;
      sl[r] = sl[r] * sc + sEa * k0;
      m0l[r] = nm0; ml[r] = nm; mnl[r] = fminf(mnl[r], tmn[r]);
    }
    __syncthreads();
  }

  // ================= finalize per-row =================
  float m0f[4], is0f[4], thf[4], crf[4];
#pragma unroll
  for (int r = 0; r < 4; ++r) {
    float m0v = m0l[r], s0 = s0l[r], m = ml[r], s = sl[r], mn = mnl[r];
#pragma unroll
    for (int off = 1; off < 16; off <<= 1) {
      float om = __shfl_xor(m0v, off), os = __shfl_xor(s0, off);
      float n0 = fmaxf(m0v, om);
      s0 = s0 * exp2f(m0v - n0) + os * exp2f(om - n0);
      m0v = n0;
      float om2 = __shfl_xor(m, off), os2 = __shfl_xor(s, off);
      float n2 = fmaxf(m, om2);
      s = s * exp2f(m - n2) + os2 * exp2f(om2 - n2);
      m = n2;
      mn = fminf(mn, __shfl_xor(mn, off));
    }
    float isf = 1.f / s;
    float amin = exp2f(mn - m) * isf;
    int rloc = 16 * w + 4 * q + r;
    float th = amin + thrS[rloc] * (isf - amin);
    if (prob[b * NTOK + i0 + rloc] >= 0.9f) th = 1e30f;
    m0f[r] = m0v; is0f[r] = 1.f / s0; thf[r] = th; crf[r] = exp2f(m0v - m) * isf;
  }

  // ================= pass 2: attn0, P, PV =================
  f32x4 oacc[4] = {};
  float denl[4] = {0.f, 0.f, 0.f, 0.f};
#pragma unroll 1
  for (int j0 = 0; j0 < NTOK; j0 += 64) {
    const unsigned short* gk = kspl + ((size_t)(bh * 16 + (j0 >> 6)) * 2) * 4096;
    const unsigned short* gv = vspl + ((size_t)(bh * 16 + (j0 >> 6)) * 2) * 4096;
#pragma unroll
    for (int jl = 0; jl < 2; ++jl) {
      int seg = 2 * w + jl;
      gload16(gk + seg * 512 + lane * 8, KhS + seg * 512);
      gload16(gk + 4096 + seg * 512 + lane * 8, KlS + seg * 512);
      gload16(gv + seg * 512 + lane * 8, VhS + seg * 512);
      gload16(gv + 4096 + seg * 512 + lane * 8, VlS + seg * 512);
    }
    if (t < 192) {
      int rl2 = t >> 6, c2 = t & 63;
      if (c2 < 63) {
        int off = (rbase - (j0 >> 5) + rl2) * 63 + c2;
        csS[rl2 * 64 + c2] = make_float2(ch[off], che[off]);
      }
    }
    __syncthreads();

    f32x4 acc[4] = {};
#pragma unroll
    for (int c = 0; c < 2; ++c) {
#pragma unroll
      for (int T = 0; T < 4; ++T) {
        int ro = (16 * T + li) * 64 + ((4 * c + q) ^ (li & 7)) * 8;
        short8 bh8 = *(const short8*)(KhS + ro);
        short8 bl8 = *(const short8*)(KlS + ro);
        acc[T] = mfma16(qah[c], bh8, acc[T]);
        acc[T] = mfma16(qah[c], bl8, acc[T]);
        acc[T] = mfma16(qal[c], bh8, acc[T]);
      }
    }

#pragma unroll
    for (int T = 0; T < 4; ++T) {
      int jj = 16 * T + li;
#pragma unroll
      for (int r = 0; r < 4; ++r) {
        int il = 16 * w + 4 * q + r;
        int rl2 = (il >> 5) - (jj >> 5) + 1;
        int cc2 = (il & 31) - (jj & 31) + 31;
        float ey = csS[rl2 * 64 + cc2].y;
        float e0 = exp2f(acc[T][r] - m0f[r]);
        __builtin_nontemporal_store(
            e0 * is0f[r],
            attn0 + (size_t)(bh * NTOK + i0 + il) * NTOK + j0 + jj);
        float at = e0 * ey * crf[r];
        float p = (at - thf[r] > 0.f) ? at : 0.f;
        denl[r] += p;
        PfS[il * 68 + jj] = p;
      }
    }
    // PV: A = P (same-wave private region), B = V^T frags
#pragma unroll
    for (int c = 0; c < 2; ++c) {
      const float* pp = PfS + (16 * w + li) * 68 + 32 * c + 8 * q;
      float pv8[8];
      *(float4*)(pv8) = *(const float4*)pp;
      *(float4*)(pv8 + 4) = *(const float4*)(pp + 4);
      short8 pah, pal;
      split8_pk(pv8, pah, pal);
#pragma unroll
      for (int T = 0; T < 4; ++T) {
        int ro = (16 * T + li) * 64 + ((4 * c + q) ^ (li & 7)) * 8;
        short8 vh8 = *(const short8*)(VhS + ro);
        short8 vl8 = *(const short8*)(VlS + ro);
        oacc[T] = mfma16(pah, vh8, oacc[T]);
        oacc[T] = mfma16(pah, vl8, oacc[T]);
        oacc[T] = mfma16(pal, vh8, oacc[T]);
      }
    }
    __syncthreads();
  }

  // scale by 1/(deno+1e-6), store o split-bf16 in [b*1024+tok][h*64+d]
#pragma unroll
  for (int r = 0; r < 4; ++r) {
    float dsum = denl[r];
#pragma unroll
    for (int off = 1; off < 16; off <<= 1) dsum += __shfl_xor(dsum, off);
    float pf = 1.f / (dsum + 1e-6f);
    int row = i0 + 16 * w + 4 * q + r;
    size_t rb2 = ((size_t)b * NTOK + row) * 512 + h * 64;
#pragma unroll
    for (int T = 0; T < 4; ++T) {
      float val = oacc[T][r] * pf;
      unsigned hv = bf16rne(val);
      float lo2 = val - __uint_as_float(hv << 16);
      oh[rb2 + 16 * T + li] = (unsigned short)hv;
      ol[rb2 + 16 * T + li] = (unsigned short)bf16rne(lo2);
    }
  }
}

// ---------------- Kernel 3: output GEMM (split-bf16 MFMA, swapped orient.) -----
// grid (4, 32). A = W_out^T [512][512], B = oh [4096][512].
// lane holds D[col = bx*128+64wr+16mt+4q+j][tok = by*128+64wc+16nt+li] -> float4.
__global__ __launch_bounds__(256, 2) void k_out(
    const unsigned short* __restrict__ wouth, const unsigned short* __restrict__ woutl,
    const unsigned short* __restrict__ oh, const unsigned short* __restrict__ ol,
    const float* __restrict__ bias, float* __restrict__ c) {
  __shared__ unsigned short AhS[8192], AlS[8192], BhS[8192], BlS[8192];
  const int bx = blockIdx.x, by = blockIdx.y;
  const int t = threadIdx.x;
  const int w = t >> 6, lane = t & 63;
  const int q = lane >> 4, li = lane & 15;
  const int wr = w >> 1, wc = w & 1;
  f32x4 acc[4][4] = {};
  gemm_core(wouth, woutl, oh, ol, bx * 128, by * 128, w, lane, acc, AhS, AlS, BhS, BlS);
#pragma unroll
  for (int mt = 0; mt < 4; ++mt) {
    int col0 = bx * 128 + 64 * wr + 16 * mt + 4 * q;
    float4 b4 = *(const float4*)(bias + col0);
#pragma unroll
    for (int nt = 0; nt < 4; ++nt) {
      int tok = by * 128 + 64 * wc + 16 * nt + li;
      float4 v;
      v.x = acc[mt][nt][0] + b4.x; v.y = acc[mt][nt][1] + b4.y;
      v.z = acc[mt][nt][2] + b4.z; v.w = acc[mt][nt][3] + b4.w;
      *(float4*)(c + (size_t)tok * 512 + col0) = v;
    }
  }
}

extern "C" void kernel_launch(void* const* d_in, const int* in_sizes, int n_in,
                              void* d_out, int out_size, void* d_ws, size_t ws_size,
                              hipStream_t stream) {
  const float* x    = (const float*)d_in[0];
  const float* prob = (const float*)d_in[1];
  const float* wqkv = (const float*)d_in[2];
  const float* t1   = (const float*)d_in[3];
  const float* t2   = (const float*)d_in[4];
  const float* sita = (const float*)d_in[5];
  const float* wt   = (const float*)d_in[6];
  const float* wout = (const float*)d_in[7];
  const float* bout = (const float*)d_in[8];
  const float* dis  = (const float*)d_in[10];

  float* out = (float*)d_out;
  float* attn0 = out + (size_t)BATCH * NTOK * 512;

  float* comb = (float*)d_ws;                          // 32768 f (log2 domain)
  float* combe = comb + 32768;                         // 32768 f
  float* qf = combe + 32768;                           // 2,097,152 f (Q fp32)
  unsigned short* kspl = (unsigned short*)(qf + (size_t)BATCH * NH * NTOK * DH);  // 8 MB
  unsigned short* vspl = kspl + (size_t)4194304;                                  // 8 MB
  unsigned short* xh = vspl + (size_t)4194304;         // 4 MB (reused as oh)
  unsigned short* xl = xh + (size_t)2097152;           // 4 MB (reused as ol)
  unsigned short* wth = xl + (size_t)2097152;          // 1.5 MB
  unsigned short* wtl = wth + (size_t)786432;          // 1.5 MB
  unsigned short* wouth = wtl + (size_t)786432;        // 0.5 MB
  unsigned short* woutl = wouth + (size_t)262144;      // 0.5 MB
  unsigned short* oh = xh;  // alias: x consumed by k_qkv before k_attn writes o
  unsigned short* ol = xl;

  hipLaunchKernelGGL(k_comb, dim3(16), dim3(256), 0, stream, t1, t2, sita, dis, comb, combe);
  hipLaunchKernelGGL(k_prep, dim3(1280), dim3(256), 0, stream,
                     x, wqkv, wout, xh, xl, wth, wtl, wouth, woutl);
  hipLaunchKernelGGL(k_qkv, dim3(12, 32), dim3(256), 0, stream,
                     xh, xl, wth, wtl, qf, kspl, vspl);
  hipLaunchKernelGGL(k_attn, dim3(16, 32), dim3(256), 0, stream,
                     qf, kspl, vspl, prob, comb, combe, wt, attn0, oh, ol);
  hipLaunchKernelGGL(k_out, dim3(4, 32), dim3(256), 0, stream,
                     wouth, woutl, oh, ol, bout, out);
}

// Round 3
// 280.518 us; speedup vs baseline: 1.3991x; 1.0030x over previous
//
#include <hip/hip_runtime.h>
#include <cmath>

#define NTOK 1024
#define NH 8
#define DH 64
#define BATCH 4
#define TBL 3969  // 63*63

#define L2E 1.4426950408889634f

typedef __attribute__((ext_vector_type(8))) short short8;
typedef __attribute__((ext_vector_type(4))) float f32x4;

__device__ __forceinline__ unsigned bf16rne(float x) {
  unsigned u = __float_as_uint(x);
  return (u + 0x7fffu + ((u >> 16) & 1u)) >> 16;
}

// pack 2 f32 -> 2 bf16 (RNE) hi parts + residual lo parts, 1 instr each pack
__device__ __forceinline__ void cvt2(float a, float b, unsigned& h, unsigned& l) {
  asm("v_cvt_pk_bf16_f32 %0, %1, %2" : "=v"(h) : "v"(a), "v"(b));
  float ra = a - __uint_as_float(h << 16);
  float rb = b - __uint_as_float(h & 0xffff0000u);
  asm("v_cvt_pk_bf16_f32 %0, %1, %2" : "=v"(l) : "v"(ra), "v"(rb));
}

__device__ __forceinline__ void split8_pk(const float* v, short8& h8, short8& l8) {
  union { short8 s; unsigned u[4]; } H, L;
#pragma unroll
  for (int j = 0; j < 4; ++j) {
    unsigned hp, lp;
    cvt2(v[2 * j], v[2 * j + 1], hp, lp);
    H.u[j] = hp; L.u[j] = lp;
  }
  h8 = H.s; l8 = L.s;
}

__device__ __forceinline__ f32x4 mfma16(short8 a, short8 b, f32x4 c) {
  return __builtin_amdgcn_mfma_f32_16x16x32_bf16(a, b, c, 0, 0, 0);
}

// global->LDS direct copy, 16B per lane (wave-uniform LDS base + lane*16)
__device__ __forceinline__ void gload16(const unsigned short* g, unsigned short* l) {
  __builtin_amdgcn_global_load_lds(
      (__attribute__((address_space(1))) unsigned int*)(g),
      (__attribute__((address_space(3))) unsigned int*)(l), 16, 0, 0);
}

// ---------------- Kernel 0: combined RPE table (log2-domain) ----------------
__global__ void k_comb(const float* __restrict__ t1, const float* __restrict__ t2,
                       const float* __restrict__ sita, const float* __restrict__ dis,
                       float* __restrict__ comb, float* __restrict__ combe) {
  int idx = blockIdx.x * 256 + threadIdx.x;
  if (idx >= TBL) return;
  int dy = idx / 63 - 31, dx = idx % 63 - 31;
  int yi = dy > 0 ? dy : 0, yj = dy > 0 ? 0 : -dy;
  int xi = dx > 0 ? dx : 0, xj = dx > 0 ? 0 : -dx;
  float dv = dis[(size_t)(yi * 32 + xi) * NTOK + (yj * 32 + xj)];
#pragma unroll
  for (int h = 0; h < NH; ++h) {
    float ita = sita[h];
    float factor = 1.0f / (2.0f * ita * ita + 1e-6f);
    float bi = t1[idx * 8 + h] * t2[idx * 8 + h];
    float v = bi + 0.01f * expf(-factor * dv);
    comb[(size_t)h * TBL + idx] = v * L2E;   // log2 domain logit
    combe[(size_t)h * TBL + idx] = expf(v);  // linear multiplicative factor
  }
}

// ---------------- Kernel 0b: convert x / transpose+convert weights -------------
__global__ __launch_bounds__(256) void k_prep(
    const float* __restrict__ x, const float* __restrict__ wqkv,
    const float* __restrict__ wout,
    unsigned short* __restrict__ xh, unsigned short* __restrict__ xl,
    unsigned short* __restrict__ wth, unsigned short* __restrict__ wtl,
    unsigned short* __restrict__ wouth, unsigned short* __restrict__ woutl) {
  const int bid = blockIdx.x;
  const int t = threadIdx.x;
  if (bid < 1024) {
    size_t base = ((size_t)bid * 256 + t) * 8;
    float v8[8];
    *(float4*)(v8) = *(const float4*)(x + base);
    *(float4*)(v8 + 4) = *(const float4*)(x + base + 4);
    short8 h8, l8;
    split8_pk(v8, h8, l8);
    *(short8*)(xh + base) = h8;
    *(short8*)(xl + base) = l8;
    return;
  }
  __shared__ float tile[64][65];
  const float* src;
  unsigned short *dh, *dl;
  int n0, k0, N;
  if (bid < 1216) {
    int b2 = bid - 1024;
    n0 = (b2 % 24) * 64; k0 = (b2 / 24) * 64; N = 1536;
    src = wqkv; dh = wth; dl = wtl;
  } else {
    int b2 = bid - 1216;
    n0 = (b2 % 8) * 64; k0 = (b2 / 8) * 64; N = 512;
    src = wout; dh = wouth; dl = woutl;
  }
#pragma unroll
  for (int l = 0; l < 4; ++l) {
    int idx = t + l * 256;
    int r = idx >> 4, c4 = idx & 15;
    float4 v = *(const float4*)(src + (size_t)(k0 + r) * N + n0 + c4 * 4);
    tile[r][c4 * 4 + 0] = v.x; tile[r][c4 * 4 + 1] = v.y;
    tile[r][c4 * 4 + 2] = v.z; tile[r][c4 * 4 + 3] = v.w;
  }
  __syncthreads();
#pragma unroll
  for (int l = 0; l < 2; ++l) {
    int idx = t + l * 256;
    int n = idx >> 3, c8 = idx & 7;
    float v8[8];
#pragma unroll
    for (int j = 0; j < 8; ++j) v8[j] = tile[c8 * 8 + j][n];
    short8 h8, l8;
    split8_pk(v8, h8, l8);
    *(short8*)(dh + (size_t)(n0 + n) * 512 + k0 + c8 * 8) = h8;
    *(short8*)(dl + (size_t)(n0 + n) * 512 + k0 + c8 * 8) = l8;
  }
}

// ---------------- shared MFMA GEMM core (split-bf16, 128x128 tile, K=512) ------
__device__ __forceinline__ void gemm_core(
    const unsigned short* pAh, const unsigned short* pAl,
    const unsigned short* pBh, const unsigned short* pBl,
    int a0, int b0, int w, int lane, f32x4 acc[4][4],
    unsigned short* AhS, unsigned short* AlS,
    unsigned short* BhS, unsigned short* BlS) {
  const int q = lane >> 4, li = lane & 15;
  const int wr = w >> 1, wc = w & 1;
#pragma unroll 1
  for (int k0 = 0; k0 < 512; k0 += 64) {
#pragma unroll
    for (int l = 0; l < 4; ++l) {
      int idx = w * 256 + l * 64 + lane;
      int row = idx >> 3, u = idx & 7;
      int so = k0 + ((u ^ (row & 7)) * 8);
      int db = (w * 256 + l * 64) * 8;
      gload16(pAh + (size_t)(a0 + row) * 512 + so, AhS + db);
      gload16(pAl + (size_t)(a0 + row) * 512 + so, AlS + db);
      gload16(pBh + (size_t)(b0 + row) * 512 + so, BhS + db);
      gload16(pBl + (size_t)(b0 + row) * 512 + so, BlS + db);
    }
    __syncthreads();
#pragma unroll
    for (int c = 0; c < 2; ++c) {
      short8 aH[4], aL[4], bH[4], bL[4];
#pragma unroll
      for (int mt = 0; mt < 4; ++mt) {
        int row = 64 * wr + 16 * mt + li;
        int ro = row * 64 + (((4 * c + q) ^ (row & 7)) * 8);
        aH[mt] = *(const short8*)(AhS + ro);
        aL[mt] = *(const short8*)(AlS + ro);
        int rowb = 64 * wc + 16 * mt + li;
        int rob = rowb * 64 + (((4 * c + q) ^ (rowb & 7)) * 8);
        bH[mt] = *(const short8*)(BhS + rob);
        bL[mt] = *(const short8*)(BlS + rob);
      }
#pragma unroll
      for (int mt = 0; mt < 4; ++mt)
#pragma unroll
        for (int nt = 0; nt < 4; ++nt) {
          acc[mt][nt] = mfma16(aH[mt], bH[nt], acc[mt][nt]);
          acc[mt][nt] = mfma16(aH[mt], bL[nt], acc[mt][nt]);
          acc[mt][nt] = mfma16(aL[mt], bH[nt], acc[mt][nt]);
        }
    }
    __syncthreads();
  }
}

// ---------------- Kernel 1: QKV GEMM (split-bf16 MFMA, XCD-swizzled) -----------
__global__ __launch_bounds__(256, 2) void k_qkv(
    const unsigned short* __restrict__ xh, const unsigned short* __restrict__ xl,
    const unsigned short* __restrict__ wth, const unsigned short* __restrict__ wtl,
    float* __restrict__ qf, unsigned short* __restrict__ kspl,
    unsigned short* __restrict__ vspl) {
  __shared__ unsigned short AhS[8192], AlS[8192], BhS[8192], BlS[8192];
  const int bid = blockIdx.x;               // 0..383
  const int lin = (bid & 7) * 48 + (bid >> 3);
  const int by = lin / 12, bx = lin % 12;   // same-by blocks colocated per XCD
  const int part = bx >> 2;
  const int t = threadIdx.x;
  const int w = t >> 6, lane = t & 63;
  const int q = lane >> 4, li = lane & 15;
  const int wr = w >> 1, wc = w & 1;
  f32x4 acc[4][4] = {};
  if (part < 2)
    gemm_core(wth, wtl, xh, xl, bx * 128, by * 128, w, lane, acc, AhS, AlS, BhS, BlS);
  else
    gemm_core(xh, xl, wth, wtl, by * 128, bx * 128, w, lane, acc, AhS, AlS, BhS, BlS);

  if (part == 0) {
    int hq = bx * 2 + wr;
#pragma unroll
    for (int nt = 0; nt < 4; ++nt) {
      int tok = by * 128 + 64 * wc + 16 * nt + li;
      int b = tok >> 10, i = tok & 1023;
#pragma unroll
      for (int mt = 0; mt < 4; ++mt) {
        int d0 = 16 * mt + 4 * q;
        float4 v;
        v.x = acc[mt][nt][0]; v.y = acc[mt][nt][1];
        v.z = acc[mt][nt][2]; v.w = acc[mt][nt][3];
        *(float4*)(qf + ((size_t)(b * NH + hq) * NTOK + i) * DH + d0) = v;
      }
    }
  } else if (part == 1) {
    int hq = bx * 2 + wr - 8;
#pragma unroll
    for (int nt = 0; nt < 4; ++nt) {
      int tok = by * 128 + 64 * wc + 16 * nt + li;
      int b = tok >> 10, tile = (tok & 1023) >> 6, tl = tok & 63;
      unsigned short* kb = kspl + ((size_t)((b * NH + hq) * 16 + tile) * 2) * 4096;
#pragma unroll
      for (int mt = 0; mt < 4; ++mt) {
        int d0 = 16 * mt + 4 * q;
        int pu = (d0 >> 3) ^ (tl & 7), off = d0 & 7;
        unsigned h0, h1, l0, l1;
        cvt2(acc[mt][nt][0], acc[mt][nt][1], h0, l0);
        cvt2(acc[mt][nt][2], acc[mt][nt][3], h1, l1);
        *(uint2*)(kb + tl * 64 + pu * 8 + off) = make_uint2(h0, h1);
        *(uint2*)(kb + 4096 + tl * 64 + pu * 8 + off) = make_uint2(l0, l1);
      }
    }
  } else {
    int hq = (bx - 8) * 2 + wc;
#pragma unroll
    for (int mt = 0; mt < 4; ++mt) {
      int tok0 = by * 128 + 64 * wr + 16 * mt + 4 * q;
      int b = tok0 >> 10, tile = (tok0 & 1023) >> 6, tl0 = tok0 & 63;
      int lu = tl0 >> 3, off = tl0 & 7;
#pragma unroll
      for (int nt = 0; nt < 4; ++nt) {
        int d = 16 * nt + li;
        unsigned short* vb = vspl + ((size_t)((b * NH + hq) * 16 + tile) * 2) * 4096;
        int pu = lu ^ (d & 7);
        unsigned h0, h1, l0, l1;
        cvt2(acc[mt][nt][0], acc[mt][nt][1], h0, l0);
        cvt2(acc[mt][nt][2], acc[mt][nt][3], h1, l1);
        *(uint2*)(vb + d * 64 + pu * 8 + off) = make_uint2(h0, h1);
        *(uint2*)(vb + 4096 + d * 64 + pu * 8 + off) = make_uint2(l0, l1);
      }
    }
  }
}

// ---------------- Kernel 2: fused attention, 8 waves, XCD-swizzled -------------
// 512 threads: wave w -> (row-group g = w>>1 [16 rows], col/d-half cw = w&1).
// QK^T + emit: wave handles T in {2cw, 2cw+1}. PV: wave contracts its own 32
// j-cols (wave-private P region) over all 64 d; O + deno merged across the
// wave pair in the epilogue via LDS.
__global__ __launch_bounds__(512, 4) void k_attn(
    const float* __restrict__ qf, const unsigned short* __restrict__ kspl,
    const unsigned short* __restrict__ vspl, const float* __restrict__ prob,
    const float* __restrict__ comb, const float* __restrict__ combe,
    const float* __restrict__ wt,
    float* __restrict__ attn0, unsigned short* __restrict__ oh,
    unsigned short* __restrict__ ol) {
  __shared__ unsigned short KhS[4096], KlS[4096];  // K [tok][d] bf16 hi/lo (swz)
  __shared__ unsigned short VhS[4096], VlS[4096];  // V^T [d][jj] bf16 hi/lo (swz)
  __shared__ float PfS[64 * 68];                   // P / merge scratch
  __shared__ float2 csS[3 * 64];                   // (comb*log2e, exp(comb))
  __shared__ float thrS[64];

  const int bid = blockIdx.x;              // 0..511
  const int lin = (bid & 7) * 64 + (bid >> 3);  // 16 row-tiles of a bh per XCD
  const int bh = lin >> 4;                 // 0..31
  const int rt = lin & 15;                 // row tile
  const int b = bh >> 3, h = bh & 7;
  const int i0 = rt * 64;
  const int t = threadIdx.x;
  const int w = t >> 6;                    // 0..7
  const int lane = t & 63;
  const int q = lane >> 4, li = lane & 15;
  const int g = w >> 1;                    // rows 16g..16g+15
  const int cw = w & 1;                    // column half (j-cols 32cw..32cw+31)
  const float* qb = qf + (size_t)bh * NTOK * DH;
  const float* ch = comb + (size_t)h * TBL;
  const float* che = combe + (size_t)h * TBL;
  const int rbase = (i0 >> 5) + 30;

  // thresh_raw = sigmoid(q . W_thresh) * sigmoid(-2)
  {
    int row = t >> 3, dg = t & 7;
    const float* qr2 = qb + (size_t)(i0 + row) * DH + dg * 8;
    float sum = 0.f;
#pragma unroll
    for (int c = 0; c < 8; ++c) sum += qr2[c] * wt[dg * 8 + c];
    sum += __shfl_xor(sum, 1);
    sum += __shfl_xor(sum, 2);
    sum += __shfl_xor(sum, 4);
    if (dg == 0)
      thrS[row] = (1.0f / (1.0f + exp2f(-sum * L2E))) * 0.11920292202211755f;
  }

  // Q fragments (A-layout: m=li, k=32c+8q+j), prescaled by 0.125*log2e
  short8 qah[2], qal[2];
  {
    const float* qr2 = qb + (size_t)(i0 + 16 * g + li) * DH;
    const float QS = 0.125f * L2E;
#pragma unroll
    for (int c = 0; c < 2; ++c) {
      float4 a = *(const float4*)(qr2 + 32 * c + 8 * q);
      float4 bb = *(const float4*)(qr2 + 32 * c + 8 * q + 4);
      float tmp[8] = {a.x * QS, a.y * QS, a.z * QS, a.w * QS,
                      bb.x * QS, bb.y * QS, bb.z * QS, bb.w * QS};
      split8_pk(tmp, qah[c], qal[c]);
    }
  }

  // per-lane online stats (log2 domain) over this wave's column half
  float m0l[4], s0l[4], ml[4], sl[4], mnl[4];
#pragma unroll
  for (int r = 0; r < 4; ++r) {
    m0l[r] = -1e30f; ml[r] = -1e30f; mnl[r] = 1e30f;
    s0l[r] = 0.f; sl[r] = 0.f;
  }

  // ================= pass 1: stats =================
#pragma unroll 1
  for (int j0 = 0; j0 < NTOK; j0 += 64) {
    const unsigned short* gk = kspl + ((size_t)(bh * 16 + (j0 >> 6)) * 2) * 4096;
    gload16(gk + w * 512 + lane * 8, KhS + w * 512);
    gload16(gk + 4096 + w * 512 + lane * 8, KlS + w * 512);
    if (t < 192) {
      int rl2 = t >> 6, c2 = t & 63;
      if (c2 < 63) {
        int off = (rbase - (j0 >> 5) + rl2) * 63 + c2;
        csS[rl2 * 64 + c2] = make_float2(ch[off], che[off]);
      }
    }
    __syncthreads();

    f32x4 acc2[2] = {};
#pragma unroll
    for (int c = 0; c < 2; ++c) {
#pragma unroll
      for (int T2 = 0; T2 < 2; ++T2) {
        int T = 2 * cw + T2;
        int ro = (16 * T + li) * 64 + ((4 * c + q) ^ (li & 7)) * 8;
        short8 bh8 = *(const short8*)(KhS + ro);
        short8 bl8 = *(const short8*)(KlS + ro);
        acc2[T2] = mfma16(qah[c], bh8, acc2[T2]);
        acc2[T2] = mfma16(qah[c], bl8, acc2[T2]);
        acc2[T2] = mfma16(qal[c], bh8, acc2[T2]);
      }
    }

    float2 ce[2][4];
    float t0[4], tt[4], tmn[4];
#pragma unroll
    for (int r = 0; r < 4; ++r) { t0[r] = -1e30f; tt[r] = -1e30f; tmn[r] = 1e30f; }
#pragma unroll
    for (int T2 = 0; T2 < 2; ++T2) {
      int jj = 16 * (2 * cw + T2) + li;
#pragma unroll
      for (int r = 0; r < 4; ++r) {
        int il = 16 * g + 4 * q + r;
        int rl2 = (il >> 5) - (jj >> 5) + 1;
        int cc2 = (il & 31) - (jj & 31) + 31;
        ce[T2][r] = csS[rl2 * 64 + cc2];
        float d0 = acc2[T2][r];
        float dt = d0 + ce[T2][r].x;
        t0[r] = fmaxf(t0[r], d0);
        tt[r] = fmaxf(tt[r], dt);
        tmn[r] = fminf(tmn[r], dt);
      }
    }
#pragma unroll
    for (int r = 0; r < 4; ++r) {
      float nm0 = fmaxf(m0l[r], t0[r]);
      float nm = fmaxf(ml[r], tt[r]);
      float sc0 = exp2f(m0l[r] - nm0), sc = exp2f(ml[r] - nm), k0 = exp2f(nm0 - nm);
      float s0a = 0.f, sEa = 0.f;
#pragma unroll
      for (int T2 = 0; T2 < 2; ++T2) {
        float e0 = exp2f(acc2[T2][r] - nm0);
        s0a += e0;
        sEa += e0 * ce[T2][r].y;
      }
      s0l[r] = s0l[r] * sc0 + s0a;
      sl[r] = sl[r] * sc + sEa * k0;
      m0l[r] = nm0; ml[r] = nm; mnl[r] = fminf(mnl[r], tmn[r]);
    }
    __syncthreads();
  }

  // ========= finalize: intra-wave (li) reduce, cross-pair merge via LDS =======
  float M0[4], S0[4], M[4], S[4], MN[4];
#pragma unroll
  for (int r = 0; r < 4; ++r) {
    float m0v = m0l[r], s0 = s0l[r], m = ml[r], s = sl[r], mn = mnl[r];
#pragma unroll
    for (int off = 1; off < 16; off <<= 1) {
      float om = __shfl_xor(m0v, off), os = __shfl_xor(s0, off);
      float n0 = fmaxf(m0v, om);
      s0 = s0 * exp2f(m0v - n0) + os * exp2f(om - n0);
      m0v = n0;
      float om2 = __shfl_xor(m, off), os2 = __shfl_xor(s, off);
      float n2 = fmaxf(m, om2);
      s = s * exp2f(m - n2) + os2 * exp2f(om2 - n2);
      m = n2;
      mn = fminf(mn, __shfl_xor(mn, off));
    }
    M0[r] = m0v; S0[r] = s0; M[r] = m; S[r] = s; MN[r] = mn;
  }
  if (li == 0) {
#pragma unroll
    for (int r = 0; r < 4; ++r) {
      int row = 16 * g + 4 * q + r;
      float* p = PfS + (cw * 64 + row) * 5;
      p[0] = M0[r]; p[1] = S0[r]; p[2] = M[r]; p[3] = S[r]; p[4] = MN[r];
    }
  }
  __syncthreads();

  float m0f[4], is0f[4], thf[4], crf[4];
#pragma unroll
  for (int r = 0; r < 4; ++r) {
    int rloc = 16 * g + 4 * q + r;
    const float* pa = PfS + rloc * 5;
    const float* pb = PfS + (64 + rloc) * 5;
    float m0v = fmaxf(pa[0], pb[0]);
    float s0 = pa[1] * exp2f(pa[0] - m0v) + pb[1] * exp2f(pb[0] - m0v);
    float m = fmaxf(pa[2], pb[2]);
    float s = pa[3] * exp2f(pa[2] - m) + pb[3] * exp2f(pb[2] - m);
    float mn = fminf(pa[4], pb[4]);
    float isf = 1.f / s;
    float amin = exp2f(mn - m) * isf;
    float th = amin + thrS[rloc] * (isf - amin);
    if (prob[b * NTOK + i0 + rloc] >= 0.9f) th = 1e30f;
    m0f[r] = m0v; is0f[r] = 1.f / s0; thf[r] = th; crf[r] = exp2f(m0v - m) * isf;
  }
  __syncthreads();  // scratch reads done before pass 2 overwrites PfS

  // ================= pass 2: attn0, P, PV =================
  f32x4 oacc[4] = {};
  float denl[4] = {0.f, 0.f, 0.f, 0.f};
#pragma unroll 1
  for (int j0 = 0; j0 < NTOK; j0 += 64) {
    const unsigned short* gk = kspl + ((size_t)(bh * 16 + (j0 >> 6)) * 2) * 4096;
    const unsigned short* gv = vspl + ((size_t)(bh * 16 + (j0 >> 6)) * 2) * 4096;
    gload16(gk + w * 512 + lane * 8, KhS + w * 512);
    gload16(gk + 4096 + w * 512 + lane * 8, KlS + w * 512);
    gload16(gv + w * 512 + lane * 8, VhS + w * 512);
    gload16(gv + 4096 + w * 512 + lane * 8, VlS + w * 512);
    if (t < 192) {
      int rl2 = t >> 6, c2 = t & 63;
      if (c2 < 63) {
        int off = (rbase - (j0 >> 5) + rl2) * 63 + c2;
        csS[rl2 * 64 + c2] = make_float2(ch[off], che[off]);
      }
    }
    __syncthreads();

    f32x4 acc2[2] = {};
#pragma unroll
    for (int c = 0; c < 2; ++c) {
#pragma unroll
      for (int T2 = 0; T2 < 2; ++T2) {
        int T = 2 * cw + T2;
        int ro = (16 * T + li) * 64 + ((4 * c + q) ^ (li & 7)) * 8;
        short8 bh8 = *(const short8*)(KhS + ro);
        short8 bl8 = *(const short8*)(KlS + ro);
        acc2[T2] = mfma16(qah[c], bh8, acc2[T2]);
        acc2[T2] = mfma16(qah[c], bl8, acc2[T2]);
        acc2[T2] = mfma16(qal[c], bh8, acc2[T2]);
      }
    }

#pragma unroll
    for (int T2 = 0; T2 < 2; ++T2) {
      int jj = 16 * (2 * cw + T2) + li;
#pragma unroll
      for (int r = 0; r < 4; ++r) {
        int il = 16 * g + 4 * q + r;
        int rl2 = (il >> 5) - (jj >> 5) + 1;
        int cc2 = (il & 31) - (jj & 31) + 31;
        float ey = csS[rl2 * 64 + cc2].y;
        float e0 = exp2f(acc2[T2][r] - m0f[r]);
        __builtin_nontemporal_store(
            e0 * is0f[r],
            attn0 + (size_t)(bh * NTOK + i0 + il) * NTOK + j0 + jj);
        float at = e0 * ey * crf[r];
        float p = (at - thf[r] > 0.f) ? at : 0.f;
        denl[r] += p;
        PfS[il * 68 + jj] = p;
      }
    }
    // PV over this wave's 32 j-cols (wave-private P region), all 64 d
    {
      const float* pp = PfS + (16 * g + li) * 68 + 32 * cw + 8 * q;
      float pv8[8];
      *(float4*)(pv8) = *(const float4*)pp;
      *(float4*)(pv8 + 4) = *(const float4*)(pp + 4);
      short8 pah, pal;
      split8_pk(pv8, pah, pal);
#pragma unroll
      for (int T = 0; T < 4; ++T) {
        int ro = (16 * T + li) * 64 + ((4 * cw + q) ^ (li & 7)) * 8;
        short8 vh8 = *(const short8*)(VhS + ro);
        short8 vl8 = *(const short8*)(VlS + ro);
        oacc[T] = mfma16(pah, vh8, oacc[T]);
        oacc[T] = mfma16(pah, vl8, oacc[T]);
        oacc[T] = mfma16(pal, vh8, oacc[T]);
      }
    }
    __syncthreads();
  }

  // ========= epilogue: merge O + deno across wave pair, store split-bf16 ======
#pragma unroll
  for (int r = 0; r < 4; ++r) {
#pragma unroll
    for (int off = 1; off < 16; off <<= 1) denl[r] += __shfl_xor(denl[r], off);
  }
  if (cw == 1) {
#pragma unroll
    for (int r = 0; r < 4; ++r) {
      int row = 16 * g + 4 * q + r;
#pragma unroll
      for (int T = 0; T < 4; ++T) PfS[row * 68 + 16 * T + li] = oacc[T][r];
      if (li == 0) PfS[row * 68 + 64] = denl[r];
    }
  }
  __syncthreads();
  if (cw == 0) {
#pragma unroll
    for (int r = 0; r < 4; ++r) {
      int rloc = 16 * g + 4 * q + r;
      float dsum = denl[r] + PfS[rloc * 68 + 64];
      float pf = 1.f / (dsum + 1e-6f);
      int row = i0 + rloc;
      size_t rb2 = ((size_t)b * NTOK + row) * 512 + h * 64;
#pragma unroll
      for (int T = 0; T < 4; ++T) {
        float val = (oacc[T][r] + PfS[rloc * 68 + 16 * T + li]) * pf;
        unsigned hv = bf16rne(val);
        float lo2 = val - __uint_as_float(hv << 16);
        oh[rb2 + 16 * T + li] = (unsigned short)hv;
        ol[rb2 + 16 * T + li] = (unsigned short)bf16rne(lo2);
      }
    }
  }
}

// ---------------- Kernel 3: output GEMM (split-bf16 MFMA, XCD-swizzled) --------
__global__ __launch_bounds__(256, 2) void k_out(
    const unsigned short* __restrict__ wouth, const unsigned short* __restrict__ woutl,
    const unsigned short* __restrict__ oh, const unsigned short* __restrict__ ol,
    const float* __restrict__ bias, float* __restrict__ c) {
  __shared__ unsigned short AhS[8192], AlS[8192], BhS[8192], BlS[8192];
  const int bid = blockIdx.x;               // 0..127
  const int lin = (bid & 7) * 16 + (bid >> 3);
  const int by = lin >> 2, bx = lin & 3;
  const int t = threadIdx.x;
  const int w = t >> 6, lane = t & 63;
  const int q = lane >> 4, li = lane & 15;
  const int wr = w >> 1, wc = w & 1;
  f32x4 acc[4][4] = {};
  gemm_core(wouth, woutl, oh, ol, bx * 128, by * 128, w, lane, acc, AhS, AlS, BhS, BlS);
#pragma unroll
  for (int mt = 0; mt < 4; ++mt) {
    int col0 = bx * 128 + 64 * wr + 16 * mt + 4 * q;
    float4 b4 = *(const float4*)(bias + col0);
#pragma unroll
    for (int nt = 0; nt < 4; ++nt) {
      int tok = by * 128 + 64 * wc + 16 * nt + li;
      float4 v;
      v.x = acc[mt][nt][0] + b4.x; v.y = acc[mt][nt][1] + b4.y;
      v.z = acc[mt][nt][2] + b4.z; v.w = acc[mt][nt][3] + b4.w;
      *(float4*)(c + (size_t)tok * 512 + col0) = v;
    }
  }
}

extern "C" void kernel_launch(void* const* d_in, const int* in_sizes, int n_in,
                              void* d_out, int out_size, void* d_ws, size_t ws_size,
                              hipStream_t stream) {
  const float* x    = (const float*)d_in[0];
  const float* prob = (const float*)d_in[1];
  const float* wqkv = (const float*)d_in[2];
  const float* t1   = (const float*)d_in[3];
  const float* t2   = (const float*)d_in[4];
  const float* sita = (const float*)d_in[5];
  const float* wt   = (const float*)d_in[6];
  const float* wout = (const float*)d_in[7];
  const float* bout = (const float*)d_in[8];
  const float* dis  = (const float*)d_in[10];

  float* out = (float*)d_out;
  float* attn0 = out + (size_t)BATCH * NTOK * 512;

  float* comb = (float*)d_ws;                          // 32768 f (log2 domain)
  float* combe = comb + 32768;                         // 32768 f
  float* qf = combe + 32768;                           // 2,097,152 f (Q fp32)
  unsigned short* kspl = (unsigned short*)(qf + (size_t)BATCH * NH * NTOK * DH);  // 8 MB
  unsigned short* vspl = kspl + (size_t)4194304;                                  // 8 MB
  unsigned short* xh = vspl + (size_t)4194304;         // 4 MB (reused as oh)
  unsigned short* xl = xh + (size_t)2097152;           // 4 MB (reused as ol)
  unsigned short* wth = xl + (size_t)2097152;          // 1.5 MB
  unsigned short* wtl = wth + (size_t)786432;          // 1.5 MB
  unsigned short* wouth = wtl + (size_t)786432;        // 0.5 MB
  unsigned short* woutl = wouth + (size_t)262144;      // 0.5 MB
  unsigned short* oh = xh;  // alias: x consumed by k_qkv before k_attn writes o
  unsigned short* ol = xl;

  hipLaunchKernelGGL(k_comb, dim3(16), dim3(256), 0, stream, t1, t2, sita, dis, comb, combe);
  hipLaunchKernelGGL(k_prep, dim3(1280), dim3(256), 0, stream,
                     x, wqkv, wout, xh, xl, wth, wtl, wouth, woutl);
  hipLaunchKernelGGL(k_qkv, dim3(384), dim3(256), 0, stream,
                     xh, xl, wth, wtl, qf, kspl, vspl);
  hipLaunchKernelGGL(k_attn, dim3(512), dim3(512), 0, stream,
                     qf, kspl, vspl, prob, comb, combe, wt, attn0, oh, ol);
  hipLaunchKernelGGL(k_out, dim3(128), dim3(256), 0, stream,
                     wouth, woutl, oh, ol, bout, out);
}